// Round 8
// baseline (60.635 us; speedup 1.0000x reference)
//
#include <hip/hip_runtime.h>

#define NQ 13
#define NBATCH 512

// Closed-form evaluation via transfer matrices (MPS, bond dim 2 -> 4 doubled).
//
// Derivation (all pieces HW-verified in rounds 3..7):
//  - After layer-0 gates, state is a product state: Psi0(b) = prod_q f_q(b_q),
//    f_q = column 0 of fused U0_q = RZ*RY*RX.
//  - CNOT chain (c->c+1) is the prefix-XOR basis permutation; its inverse is
//    Gray: Psi1(d) = prod_q f_q(d_q ^ d_{q-1})  (d_{-1}=0).
//  - Layer-1 gates U1_q act per qubit; second chain + PauliZ(q*) fold into
//    signs (-1)^{c_0^..^c_{q*}}:
//      ev[q*] = sum_{d,d'} prod_q G_q(d_q,d'_q) f_q(d_q^d_{q-1}) f*_q(d'_q^d'_{q-1})
//      G_q(a,b) = sum_c s_c U1_q[c][a] conj(U1_q[c][b]),  s_c=(-1)^c iff q<=q*.
//  - This is a 4-state (a,b) transfer contraction. For q>q* unitarity gives
//    G = delta_ab and the tail telescopes (Markov, row sums 1) to a cap:
//      q*<12: ev = (l00+l11) + gamma*(l01+l10), gamma = 2 Re(f0 conj(f1)) at q*+1
//      q*=12: ev = l00+l11+l01+l10
//  - l is Hermitian (l10 = conj(l01), diag real); ev is real.
//
// One wave per batch element; lane = q* (lanes 13..63 idle-compute, no store).
// No LDS, no barriers, no shuffles. Inputs are block-uniform -> scalar loads.
__global__ __launch_bounds__(64) void qsim_kernel(const float* __restrict__ x,
                                                  const float* __restrict__ w,
                                                  float* __restrict__ out) {
    const int b = blockIdx.x;
    const int lane = threadIdx.x;
    const int qs = lane < NQ ? lane : NQ - 1;

    // l[(a,b)]: doubled-bond transfer state, init l[(0,0)] = 1
    float l00r = 1.f, l00i = 0.f;
    float l01r = 0.f, l01i = 0.f;
    float l10r = 0.f, l10i = 0.f;
    float l11r = 0.f, l11i = 0.f;
    float ev = 0.f;

    const float* xb = x + b * NQ;

    #pragma unroll
    for (int q = 0; q < NQ; ++q) {
        const float xv = xb[q];
        // ---- layer-0 fused gate U0_q, column 0 -> f0,f1 ----
        float sx, cx, sy, cy, sz, cz;
        __sincosf(0.5f * xv * w[q * 3 + 0], &sx, &cx);
        __sincosf(0.5f * xv * w[q * 3 + 1], &sy, &cy);
        __sincosf(0.5f * w[q * 3 + 2], &sz, &cz);
        const float a0r = cy * cx, a0i = sy * sx;        // (RY*RX)00
        const float a1r = sy * cx, a1i = -cy * sx;       // (RY*RX)10
        const float f0r = a0r * cz + a0i * sz, f0i = a0i * cz - a0r * sz;
        const float f1r = a1r * cz - a1i * sz, f1i = a1i * cz + a1r * sz;

        if (q <= qs) {
            // ---- layer-1 fused gate U1_q (full 2x2) ----
            float sx1, cx1, sy1, cy1, sz1, cz1;
            __sincosf(0.5f * xv * w[(NQ + q) * 3 + 0], &sx1, &cx1);
            __sincosf(0.5f * xv * w[(NQ + q) * 3 + 1], &sy1, &cy1);
            __sincosf(0.5f * w[(NQ + q) * 3 + 2], &sz1, &cz1);
            const float m00r = cy1 * cx1,  m00i = sy1 * sx1;
            const float m01r = -sy1 * cx1, m01i = -cy1 * sx1;
            const float m10r = sy1 * cx1,  m10i = -cy1 * sx1;
            const float m11r = cy1 * cx1,  m11i = -sy1 * sx1;
            const float u00r = m00r * cz1 + m00i * sz1, u00i = m00i * cz1 - m00r * sz1;
            const float u01r = m01r * cz1 + m01i * sz1, u01i = m01i * cz1 - m01r * sz1;
            const float u10r = m10r * cz1 - m10i * sz1, u10i = m10i * cz1 + m10r * sz1;
            const float u11r = m11r * cz1 - m11i * sz1, u11i = m11i * cz1 + m11r * sz1;
            // G(a,b) = U[0][a]conj(U[0][b]) - U[1][a]conj(U[1][b])
            // G00,G11 real; G10 = conj(G01)
            const float G00  = u00r*u00r + u00i*u00i - u10r*u10r - u10i*u10i;
            const float G11  = u01r*u01r + u01i*u01i - u11r*u11r - u11i*u11i;
            const float G01r = u00r*u01r + u00i*u01i - (u10r*u11r + u10i*u11i);
            const float G01i = u00i*u01r - u00r*u01i - (u10i*u11r - u10r*u11i);
            // m[ap][b] = conj(f_b)*l[ap][0] + conj(f_{1-b})*l[ap][1]
            const float m00_r = f0r*l00r + f0i*l00i + f1r*l01r + f1i*l01i;
            const float m00_i = f0r*l00i - f0i*l00r + f1r*l01i - f1i*l01r;
            const float m01_r = f1r*l00r + f1i*l00i + f0r*l01r + f0i*l01i;
            const float m01_i = f1r*l00i - f1i*l00r + f0r*l01i - f0i*l01r;
            const float m10_r = f0r*l10r + f0i*l10i + f1r*l11r + f1i*l11i;
            const float m10_i = f0r*l10i - f0i*l10r + f1r*l11i - f1i*l11r;
            const float m11_r = f1r*l10r + f1i*l10i + f0r*l11r + f0i*l11i;
            const float m11_i = f1r*l10i - f1i*l10r + f0r*l11i - f0i*l11r;
            // n[a][b] = f_a*m[0][b] + f_{1-a}*m[1][b]
            const float n00_r = f0r*m00_r - f0i*m00_i + f1r*m10_r - f1i*m10_i;
            const float n00_i = f0r*m00_i + f0i*m00_r + f1r*m10_i + f1i*m10_r;
            const float n01_r = f0r*m01_r - f0i*m01_i + f1r*m11_r - f1i*m11_i;
            const float n01_i = f0r*m01_i + f0i*m01_r + f1r*m11_i + f1i*m11_r;
            const float n10_r = f1r*m00_r - f1i*m00_i + f0r*m10_r - f0i*m10_i;
            const float n10_i = f1r*m00_i + f1i*m00_r + f0r*m10_i + f0i*m10_r;
            const float n11_r = f1r*m01_r - f1i*m01_i + f0r*m11_r - f0i*m11_i;
            const float n11_i = f1r*m01_i + f1i*m01_r + f0r*m11_i + f0i*m11_r;
            // l = G .* n   (G10 = conj(G01))
            l00r = G00 * n00_r;                  l00i = G00 * n00_i;
            l11r = G11 * n11_r;                  l11i = G11 * n11_i;
            l01r = G01r * n01_r - G01i * n01_i;  l01i = G01r * n01_i + G01i * n01_r;
            l10r = G01r * n10_r + G01i * n10_i;  l10i = G01r * n10_i - G01i * n10_r;
        } else if (q == qs + 1) {
            // unsigned-tail cap: first unsigned step contracts, rest preserve
            const float gamma = 2.0f * (f0r * f1r + f0i * f1i);
            ev = l00r + l11r + gamma * (l01r + l10r);
        }
    }
    if (qs == NQ - 1) ev = l00r + l11r + l01r + l10r;
    if (lane < NQ) out[b * NQ + lane] = ev;
}

extern "C" void kernel_launch(void* const* d_in, const int* in_sizes, int n_in,
                              void* d_out, int out_size, void* d_ws, size_t ws_size,
                              hipStream_t stream) {
    const float* x = (const float*)d_in[0];   // (512, 13) float32
    const float* w = (const float*)d_in[1];   // (2, 13, 3) float32
    float* out = (float*)d_out;               // (512, 13) float32
    qsim_kernel<<<NBATCH, 64, 0, stream>>>(x, w, out);
}